// Round 9
// baseline (159.426 us; speedup 1.0000x reference)
//
#include <hip/hip_runtime.h>

typedef __bf16 bf16x8 __attribute__((ext_vector_type(8)));
typedef float f32x4 __attribute__((ext_vector_type(4)));
typedef float f32x16 __attribute__((ext_vector_type(16)));
typedef unsigned short u16x8 __attribute__((ext_vector_type(8)));
typedef unsigned short u16x4 __attribute__((ext_vector_type(4)));
typedef unsigned u32x4 __attribute__((ext_vector_type(4)));

#define BB 4
#define TT 2048
#define CC 1024
#define HH 16
#define DD 64

__device__ __forceinline__ unsigned short f2bf(float f){
  unsigned u = __builtin_bit_cast(unsigned, f);
  u += 0x7FFFu + ((u >> 16) & 1u);
  return (unsigned short)(u >> 16);
}
__device__ __forceinline__ bf16x8 as_bf(u16x8 v){ return __builtin_bit_cast(bf16x8, v); }
__device__ __forceinline__ unsigned cvt_pk(float lo, float hi){
  unsigned r; asm("v_cvt_pk_bf16_f32 %0, %1, %2" : "=v"(r) : "v"(lo), "v"(hi)); return r;
}
__device__ __forceinline__ void pl32swap(unsigned &a, unsigned &b){
  asm("v_permlane32_swap_b32 %0, %1" : "+v"(a), "+v"(b));
}
__device__ __forceinline__ float ex2(float x){
#if __has_builtin(__builtin_amdgcn_exp2f)
  return __builtin_amdgcn_exp2f(x);
#else
  return __expf(x * 0.6931471805599453f);
#endif
}

// all 5 fp32->bf16 conversions in one launch
__global__ __launch_bounds__(256) void cvt_all(const float* __restrict__ x,
                                               const float* __restrict__ Wk,
                                               const float* __restrict__ Wq,
                                               const float* __restrict__ Wv,
                                               const float* __restrict__ Wp,
                                               unsigned short* __restrict__ xb,
                                               unsigned short* __restrict__ wb){
  const int i = blockIdx.x * 256 + threadIdx.x;           // one float4 per thread
  constexpr int EX = (BB*TT*CC)/4;                        // 2,097,152
  const float* src; unsigned short* dst; int off;
  if (i < EX){ src = x; dst = xb; off = i; }
  else {
    const int j = i - EX;
    const int wsel = j >> 18;                             // Wn/4 = 2^18
    off = j & 262143;
    src = (wsel==0) ? Wk : (wsel==1) ? Wq : (wsel==2) ? Wv : Wp;
    dst = wb + ((size_t)wsel << 20);                      // Wn = 2^20
  }
  const float4 f = ((const float4*)src)[off];
  u16x4 o; o.x = f2bf(f.x); o.y = f2bf(f.y); o.z = f2bf(f.z); o.w = f2bf(f.w);
  ((u16x4*)dst)[off] = o;
}

// C = A @ B^T, A: 8192xK row-major bf16, B: (NX*128)xK row-major bf16.
// Proven single-buffer 2-barrier structure; main loop UNIFORM for all blocks.
// QKV=true: tsel 0 -> K rows to o0 (bf16), tsel 1 -> Q rows to o1 (bf16, *log2e/8),
//           tsel 2 -> V written TRANSPOSED in the epilogue only (u16x4 runs along t)
//           to o2 = Vt [B*H][D][T] with the attn XOR k-chunk swizzle.
// QKV=false: f32 out to o0.
template<int NX, bool QKV>
__global__ __launch_bounds__(256) void gemm128(const unsigned short* __restrict__ A,
                                               const unsigned short* __restrict__ Bm,
                                               void* __restrict__ o0, void* __restrict__ o1,
                                               void* __restrict__ o2){
  constexpr int K = 1024;
  constexpr int NWG = NX * 64;
  __shared__ __align__(16) unsigned short As[128*64];
  __shared__ __align__(16) unsigned short Bs[128*64];
  const int tid = threadIdx.x;
  const int flat = blockIdx.y * NX + blockIdx.x;
  const int swz = (flat & 7) * (NWG / 8) + (flat >> 3);   // bijective XCD swizzle
  const int n0 = (swz % NX) * 128;
  const int m0 = (swz / NX) * 128;
  const int w = tid >> 6, lane = tid & 63, l15 = lane & 15, g = lane >> 4;
  const int wm = (w >> 1) * 64, wn = (w & 1) * 64;
  const int tsel = QKV ? (n0 >> 10) : 0;                  // block-uniform

  f32x4 acc[4][4] = {};

  for (int k0 = 0; k0 < K; k0 += 64){
    #pragma unroll
    for (int i = 0; i < 4; ++i){
      const int p = i*256 + tid;
      const int r = p >> 3, c = p & 7;
      const int gc = c ^ (r & 7);
      __builtin_amdgcn_global_load_lds(
        (const __attribute__((address_space(1))) void*)(A + (size_t)(m0 + r)*K + k0 + gc*8),
        (__attribute__((address_space(3))) void*)(As + p*8), 16, 0, 0);
    }
    #pragma unroll
    for (int i = 0; i < 4; ++i){
      const int p = i*256 + tid;
      const int r = p >> 3, c = p & 7;
      const int gc = c ^ (r & 7);
      __builtin_amdgcn_global_load_lds(
        (const __attribute__((address_space(1))) void*)(Bm + (size_t)(n0 + r)*K + k0 + gc*8),
        (__attribute__((address_space(3))) void*)(Bs + p*8), 16, 0, 0);
    }
    __syncthreads();

    bf16x8 af[2][4], bfr[2][4];
    #pragma unroll
    for (int ks = 0; ks < 2; ++ks){
      #pragma unroll
      for (int m = 0; m < 4; ++m){
        const int R = wm + m*16 + l15;
        const int c = (ks*4 + g) ^ (R & 7);
        af[ks][m] = as_bf(*(const u16x8*)(As + R*64 + c*8));
      }
      #pragma unroll
      for (int n = 0; n < 4; ++n){
        const int R = wn + n*16 + l15;
        const int c = (ks*4 + g) ^ (R & 7);
        bfr[ks][n] = as_bf(*(const u16x8*)(Bs + R*64 + c*8));
      }
    }
    #pragma unroll
    for (int ks = 0; ks < 2; ++ks)
      #pragma unroll
      for (int m = 0; m < 4; ++m)
        #pragma unroll
        for (int n = 0; n < 4; ++n)
          acc[m][n] = __builtin_amdgcn_mfma_f32_16x16x32_bf16(af[ks][m], bfr[ks][n], acc[m][n], 0, 0, 0);
    __syncthreads();
  }

  if (QKV && tsel == 2){
    // V epilogue: write transposed to Vt [B*H][D][T] with XOR k-chunk swizzle.
    // acc[m][n][r] = C[t][c], t = m0loc+wm+m*16+g*4+r, c = n0loc+wn+n*16+l15.
    // Each (m,n) gives a 4-run along t inside one 8-elem chunk -> u16x4 store.
    const int bq = m0 >> 11;                  // batch
    const int t0 = m0 & 2047;
    unsigned short* vt = (unsigned short*)o2;
    #pragma unroll
    for (int n = 0; n < 4; ++n){
      const int cg = (n0 & 1023) + wn + n*16 + l15;       // channel 0..1023
      const int h = cg >> 6, d = cg & 63;
      unsigned short* base = vt + ((size_t)(bq*HH + h)*DD + d)*TT;
      #pragma unroll
      for (int m = 0; m < 4; ++m){
        const int t = t0 + wm + m*16 + g*4;
        const int kt = t >> 6;
        const int cch = ((t >> 3) & 7) ^ (d & 7);
        u16x4 pv;
        pv.x = f2bf(acc[m][n][0]); pv.y = f2bf(acc[m][n][1]);
        pv.z = f2bf(acc[m][n][2]); pv.w = f2bf(acc[m][n][3]);
        *(u16x4*)(base + (size_t)kt*64 + cch*8 + (t & 7)) = pv;
      }
    }
    return;
  }

  const float sc = (QKV && tsel == 1) ? 0.18033688011112042f : 1.0f;  // log2(e)/8
  unsigned short* outb = nullptr;
  if (QKV) outb = (unsigned short*)(tsel == 0 ? o0 : o1);

  #pragma unroll
  for (int m = 0; m < 4; ++m)
    #pragma unroll
    for (int n = 0; n < 4; ++n)
      #pragma unroll
      for (int r = 0; r < 4; ++r){
        const int row = m0 + wm + m*16 + g*4 + r;
        const int col = n0 + wn + n*16 + l15;
        const float v = acc[m][n][r];
        if (QKV) outb[(size_t)row*1024 + (col & 1023)] = f2bf(v * sc);
        else     ((float*)o0)[(size_t)row*1024 + col] = v;
      }
}

// Causal flash attention, swapped-QK 32x32, 8 waves x 32 q-rows = 256 q-rows/block.
// R6-proven: 3-buffer ring, counted vmcnt(2), balanced strip pairing.
// Q,K: [B,T,C] bf16 (Q pre-scaled by log2e/8); Vt: [B*H][D][T] swizzled; Y: [B,T,C] bf16
__global__ __launch_bounds__(512, 4) void attn2(const unsigned short* __restrict__ Q,
                                                const unsigned short* __restrict__ Km,
                                                const unsigned short* __restrict__ Vt,
                                                unsigned short* __restrict__ Y){
  __shared__ __align__(16) unsigned short Ks[3][64*64];
  __shared__ __align__(16) unsigned short Vs[3][64*64];
  const int bh = blockIdx.x, b = bh >> 4, h = bh & 15;
  const int yq = blockIdx.y;
  const int qt = (yq < 4) ? (7 - yq) : (yq - 4);  // pairs (7,0),(6,1),(5,2),(4,3) per CU
  const int tid = threadIdx.x;
  const int w = tid >> 6, lane = tid & 63, l31 = lane & 31, hi = lane >> 5;
  const int q0 = qt * 256;
  const int wq0 = q0 + w * 32;
  const int wqmax = wq0 + 31;
  const int nkt = 4 * qt + 4;
  const int qg = wq0 + l31;

  const unsigned short* Ksrc = Km + (size_t)b*TT*CC + h*DD;
  const unsigned short* Vsrc = Vt + (size_t)bh*DD*TT;

  auto stage = [&](int buf, int kt){
    const int r = tid >> 3, c = tid & 7;
    const int gc = c ^ (r & 7);
    __builtin_amdgcn_global_load_lds(
      (const __attribute__((address_space(1))) void*)(Ksrc + (size_t)(kt*64 + r)*CC + gc*8),
      (__attribute__((address_space(3))) void*)(&Ks[buf][tid*8]), 16, 0, 0);
    __builtin_amdgcn_global_load_lds(
      (const __attribute__((address_space(1))) void*)(Vsrc + (size_t)r*TT + (size_t)kt*64 + c*8),
      (__attribute__((address_space(3))) void*)(&Vs[buf][tid*8]), 16, 0, 0);
  };

  stage(0, 0);

  // Q fragments (B-operand): q = l31, d = 16*ds + 8*hi + j
  const unsigned short* qrow = Q + ((size_t)b*TT + wq0 + l31)*CC + h*DD;
  bf16x8 qf[4];
  #pragma unroll
  for (int ds = 0; ds < 4; ++ds)
    qf[ds] = as_bf(*(const u16x8*)(qrow + 16*ds + 8*hi));

  // LDS fragment offsets (elements); same for K and V tiles, +2048 for rows 32..63
  int koff[4];
  #pragma unroll
  for (int ds = 0; ds < 4; ++ds)
    koff[ds] = l31*64 + (((2*ds + hi) ^ (l31 & 7)) * 8);

  float m_ = -1e30f, l_ = 0.f;
  f32x16 y0 = {}, y1 = {};

  int cb = 0;
  for (int t = 0; t < nkt; ++t){
    const int nx = (cb == 2) ? 0 : cb + 1;
    if (t + 1 < nkt){
      stage(nx, t + 1);
      asm volatile("s_waitcnt vmcnt(2)" ::: "memory");
    } else {
      asm volatile("s_waitcnt vmcnt(0)" ::: "memory");
    }
    __builtin_amdgcn_s_barrier();

    if (t*64 <= wqmax){
      const unsigned short* Kp = &Ks[cb][0];
      const unsigned short* Vp = &Vs[cb][0];

      // S^T = K . Q^T : lane holds q-col (l31), 32 k-rows across regs+hi
      f32x16 s0 = {}, s1 = {};
      __builtin_amdgcn_s_setprio(1);
      #pragma unroll
      for (int ds = 0; ds < 4; ++ds){
        bf16x8 kf0 = as_bf(*(const u16x8*)(Kp + koff[ds]));
        s0 = __builtin_amdgcn_mfma_f32_32x32x16_bf16(kf0, qf[ds], s0, 0, 0, 0);
        bf16x8 kf1 = as_bf(*(const u16x8*)(Kp + koff[ds] + 2048));
        s1 = __builtin_amdgcn_mfma_f32_32x32x16_bf16(kf1, qf[ds], s1, 0, 0, 0);
      }
      __builtin_amdgcn_s_setprio(0);

      if (t*64 + 63 > wq0){   // boundary tiles: causal mask (k_g > q_g)
        const int kb0 = t*64;
        #pragma unroll
        for (int r = 0; r < 16; ++r){
          const int kr = (r & 3) + 8*(r >> 2) + 4*hi;
          if (kb0 + kr      > qg) s0[r] = -1e30f;
          if (kb0 + 32 + kr > qg) s1[r] = -1e30f;
        }
      }

      // tree max over 32 scores, then lane-pair merge
      float tm[8];
      #pragma unroll
      for (int r = 0; r < 8; ++r) tm[r] = fmaxf(fmaxf(s0[r], s0[r+8]), fmaxf(s1[r], s1[r+8]));
      #pragma unroll
      for (int r = 0; r < 4; ++r) tm[r] = fmaxf(tm[r], tm[r+4]);
      float pmax = fmaxf(fmaxf(tm[0], tm[2]), fmaxf(tm[1], tm[3]));
      pmax = fmaxf(pmax, __shfl_xor(pmax, 32));

      // defer-max rescale (log2 domain, THR=8 -> P <= 256)
      if (!__all(pmax <= m_ + 8.f)){
        const float mnew = fmaxf(m_, pmax);
        const float alpha = ex2(m_ - mnew);
        l_ *= alpha;
        #pragma unroll
        for (int r = 0; r < 16; ++r){
          const float ar = __shfl(alpha, (r & 3) + 8*(r >> 2) + 4*hi);
          y0[r] *= ar; y1[r] *= ar;
        }
        m_ = mnew;
      }

      #pragma unroll
      for (int r = 0; r < 16; ++r) s0[r] = ex2(s0[r] - m_);
      #pragma unroll
      for (int r = 0; r < 16; ++r) s1[r] = ex2(s1[r] - m_);
      float ts[8];
      #pragma unroll
      for (int r = 0; r < 8; ++r) ts[r] = (s0[r] + s0[r+8]) + (s1[r] + s1[r+8]);
      #pragma unroll
      for (int r = 0; r < 4; ++r) ts[r] += ts[r+4];
      float rs = (ts[0] + ts[2]) + (ts[1] + ts[3]);
      rs += __shfl_xor(rs, 32);
      l_ += rs;

      // P -> A-frags (cvt_pk + permlane32_swap), fused with PV MFMA
      __builtin_amdgcn_s_setprio(1);
      #pragma unroll
      for (int m = 0; m < 4; ++m){
        const f32x16 c = (m < 2) ? s0 : s1;
        const int bx = (m & 1) * 8;
        unsigned A0 = cvt_pk(c[bx+0], c[bx+1]);
        unsigned B0 = cvt_pk(c[bx+4], c[bx+5]);
        pl32swap(A0, B0);
        unsigned A1 = cvt_pk(c[bx+2], c[bx+3]);
        unsigned B1 = cvt_pk(c[bx+6], c[bx+7]);
        pl32swap(A1, B1);
        u32x4 pw; pw.x = A0; pw.y = A1; pw.z = B0; pw.w = B1;
        const bf16x8 pa = __builtin_bit_cast(bf16x8, pw);
        bf16x8 vf0 = as_bf(*(const u16x8*)(Vp + koff[m]));
        y0 = __builtin_amdgcn_mfma_f32_32x32x16_bf16(pa, vf0, y0, 0, 0, 0);
        bf16x8 vf1 = as_bf(*(const u16x8*)(Vp + koff[m] + 2048));
        y1 = __builtin_amdgcn_mfma_f32_32x32x16_bf16(pa, vf1, y1, 0, 0, 0);
      }
      __builtin_amdgcn_s_setprio(0);
    }
    cb = nx;
  }

  const float linv = 1.f / l_;
  #pragma unroll
  for (int r = 0; r < 16; ++r){
    const int qlr = (r & 3) + 8*(r >> 2) + 4*hi;
    const float lr = __shfl(linv, qlr);
    unsigned short* yp = Y + ((size_t)b*TT + wq0 + qlr)*CC + h*DD + l31;
    yp[0]  = f2bf(y0[r] * lr);
    yp[32] = f2bf(y1[r] * lr);
  }
}

extern "C" void kernel_launch(void* const* d_in, const int* in_sizes, int n_in,
                              void* d_out, int out_size, void* d_ws, size_t ws_size,
                              hipStream_t stream){
  const float* x  = (const float*)d_in[0];
  const float* Wk = (const float*)d_in[1];
  const float* Wq = (const float*)d_in[2];
  const float* Wv = (const float*)d_in[3];
  const float* Wp = (const float*)d_in[4];

  const size_t E  = (size_t)BB*TT*CC;
  const size_t Wn = (size_t)CC*CC;
  unsigned short* ws  = (unsigned short*)d_ws;
  unsigned short* xb  = ws;                 // reused as yb after attention
  unsigned short* wkb = xb  + E;            // wkb,wqb,wvb contiguous = B[3072][1024]
  unsigned short* wqb = wkb + Wn;
  unsigned short* wvb = wqb + Wn;
  unsigned short* wpb = wvb + Wn;
  unsigned short* qb  = wpb + Wn;
  unsigned short* kb  = qb  + E;
  unsigned short* vt  = kb  + E;            // V written transposed by QKV GEMM

  cvt_all<<<12288, 256, 0, stream>>>(x, Wk, Wq, Wv, Wp, xb, wkb);

  // fused QKV: B = [Wk; Wq; Wv] (3072x1024) -> kb, qb (scaled), vt (transposed+swizzled)
  gemm128<24, true><<<dim3(24, 64), 256, 0, stream>>>(xb, wkb, kb, qb, vt);

  unsigned short* yb = xb;
  attn2<<<dim3(BB*HH, TT/256), 512, 0, stream>>>(qb, kb, vt, yb);

  gemm128<8, false><<<dim3(8, 64), 256, 0, stream>>>(yb, wpb, (float*)d_out, nullptr, nullptr);
}

// Round 10
// 158.724 us; speedup vs baseline: 1.0044x; 1.0044x over previous
//
#include <hip/hip_runtime.h>

typedef __bf16 bf16x8 __attribute__((ext_vector_type(8)));
typedef float f32x4 __attribute__((ext_vector_type(4)));
typedef float f32x16 __attribute__((ext_vector_type(16)));
typedef unsigned short u16x8 __attribute__((ext_vector_type(8)));
typedef unsigned short u16x4 __attribute__((ext_vector_type(4)));
typedef unsigned u32x4 __attribute__((ext_vector_type(4)));

#define BB 4
#define TT 2048
#define CC 1024
#define HH 16
#define DD 64

__device__ __forceinline__ unsigned short f2bf(float f){
  unsigned u = __builtin_bit_cast(unsigned, f);
  u += 0x7FFFu + ((u >> 16) & 1u);
  return (unsigned short)(u >> 16);
}
__device__ __forceinline__ bf16x8 as_bf(u16x8 v){ return __builtin_bit_cast(bf16x8, v); }
__device__ __forceinline__ unsigned cvt_pk(float lo, float hi){
  unsigned r; asm("v_cvt_pk_bf16_f32 %0, %1, %2" : "=v"(r) : "v"(lo), "v"(hi)); return r;
}
__device__ __forceinline__ void pl32swap(unsigned &a, unsigned &b){
  asm("v_permlane32_swap_b32 %0, %1" : "+v"(a), "+v"(b));
}
__device__ __forceinline__ float ex2(float x){
#if __has_builtin(__builtin_amdgcn_exp2f)
  return __builtin_amdgcn_exp2f(x);
#else
  return __expf(x * 0.6931471805599453f);
#endif
}

// all 5 fp32->bf16 conversions in one launch
__global__ __launch_bounds__(256) void cvt_all(const float* __restrict__ x,
                                               const float* __restrict__ Wk,
                                               const float* __restrict__ Wq,
                                               const float* __restrict__ Wv,
                                               const float* __restrict__ Wp,
                                               unsigned short* __restrict__ xb,
                                               unsigned short* __restrict__ wb){
  const int i = blockIdx.x * 256 + threadIdx.x;           // one float4 per thread
  constexpr int EX = (BB*TT*CC)/4;                        // 2,097,152
  const float* src; unsigned short* dst; int off;
  if (i < EX){ src = x; dst = xb; off = i; }
  else {
    const int j = i - EX;
    const int wsel = j >> 18;                             // Wn/4 = 2^18
    off = j & 262143;
    src = (wsel==0) ? Wk : (wsel==1) ? Wq : (wsel==2) ? Wv : Wp;
    dst = wb + ((size_t)wsel << 20);                      // Wn = 2^20
  }
  const float4 f = ((const float4*)src)[off];
  u16x4 o; o.x = f2bf(f.x); o.y = f2bf(f.y); o.z = f2bf(f.z); o.w = f2bf(f.w);
  ((u16x4*)dst)[off] = o;
}

// ---------------- 256x256 QKV GEMM, dbuf + counted vmcnt pipeline ----------------
// C = A @ B^T, A: 8192x1024 bf16, B: 3072x1024 bf16 ([Wk;Wq;Wv]).
// 512 thr = 8 waves (2M x 4N), per-wave 128x64 output. LDS: 2 slots x (A 256x64 + B 256x64)
// = 128 KB dynamic. Per K-tile: stage(t+1) -> vmcnt(8) -> barrier -> ds_read+MFMA
// -> lgkmcnt(0)+barrier. tsel 0 -> K (o0), 1 -> Q (o1, *log2e/8), 2 -> V transposed (o2=Vt).
template<int NX>
__global__ __launch_bounds__(512) void gemm256q(const unsigned short* __restrict__ A,
                                                const unsigned short* __restrict__ Bm,
                                                void* __restrict__ o0, void* __restrict__ o1,
                                                void* __restrict__ o2){
  constexpr int K = 1024;
  constexpr int NKT = 16;
  constexpr int NWG = NX * 32;
  extern __shared__ unsigned short lds[];                 // 2 x 32768 elems
  const int tid = threadIdx.x;
  const int flat = blockIdx.y * NX + blockIdx.x;
  const int swz = (flat & 7) * (NWG / 8) + (flat >> 3);   // bijective (NWG%8==0)
  const int n0 = (swz % NX) * 256;
  const int m0 = (swz / NX) * 256;
  const int w = tid >> 6, lane = tid & 63, l15 = lane & 15, g = lane >> 4;
  const int wm = (w >> 2) * 128;                          // {0,128}
  const int wn = (w & 3) * 64;                            // {0,64,128,192}
  const int tsel = n0 >> 10;                              // block-uniform

  auto stage = [&](int s, int kt){
    unsigned short* Asl = lds + s*32768;
    unsigned short* Bsl = Asl + 16384;
    const int k0 = kt * 64;
    #pragma unroll
    for (int i = 0; i < 4; ++i){
      const int p = i*512 + tid;
      const int r = p >> 3, c = p & 7;
      const int gc = c ^ (r & 7);
      __builtin_amdgcn_global_load_lds(
        (const __attribute__((address_space(1))) void*)(A + (size_t)(m0 + r)*K + k0 + gc*8),
        (__attribute__((address_space(3))) void*)(Asl + p*8), 16, 0, 0);
    }
    #pragma unroll
    for (int i = 0; i < 4; ++i){
      const int p = i*512 + tid;
      const int r = p >> 3, c = p & 7;
      const int gc = c ^ (r & 7);
      __builtin_amdgcn_global_load_lds(
        (const __attribute__((address_space(1))) void*)(Bm + (size_t)(n0 + r)*K + k0 + gc*8),
        (__attribute__((address_space(3))) void*)(Bsl + p*8), 16, 0, 0);
    }
  };

  f32x4 acc[8][4] = {};
  stage(0, 0);

  for (int t = 0; t < NKT; ++t){
    const int s = t & 1;
    if (t + 1 < NKT){
      stage(s ^ 1, t + 1);                                 // into slot freed at t-1's barrier
      asm volatile("s_waitcnt vmcnt(8)" ::: "memory");     // tile t landed; t+1 in flight
    } else {
      asm volatile("s_waitcnt vmcnt(0)" ::: "memory");
    }
    __builtin_amdgcn_s_barrier();                          // all threads' tile-t loads visible

    const unsigned short* Asl = lds + s*32768;
    const unsigned short* Bsl = Asl + 16384;

    #pragma unroll
    for (int ks = 0; ks < 2; ++ks){
      bf16x8 b4[4];
      #pragma unroll
      for (int n = 0; n < 4; ++n){
        const int R = wn + n*16 + l15;
        const int c = (ks*4 + g) ^ (R & 7);
        b4[n] = as_bf(*(const u16x8*)(Bsl + R*64 + c*8));
      }
      __builtin_amdgcn_s_setprio(1);
      #pragma unroll
      for (int m = 0; m < 8; ++m){
        const int R = wm + m*16 + l15;
        const int c = (ks*4 + g) ^ (R & 7);
        bf16x8 a = as_bf(*(const u16x8*)(Asl + R*64 + c*8));
        #pragma unroll
        for (int n = 0; n < 4; ++n)
          acc[m][n] = __builtin_amdgcn_mfma_f32_16x16x32_bf16(a, b4[n], acc[m][n], 0, 0, 0);
      }
      __builtin_amdgcn_s_setprio(0);
    }

    asm volatile("s_waitcnt lgkmcnt(0)" ::: "memory");     // all reads of slot s complete
    __builtin_amdgcn_s_barrier();                          // before next stage overwrites
  }

  if (tsel == 2){
    // V epilogue: write transposed to Vt [B*H][D][T] with XOR k-chunk swizzle (u16x4 runs).
    const int bq = m0 >> 11;
    const int t0 = m0 & 2047;
    unsigned short* vt = (unsigned short*)o2;
    #pragma unroll
    for (int n = 0; n < 4; ++n){
      const int cg = (n0 & 1023) + wn + n*16 + l15;        // channel 0..1023
      const int h = cg >> 6, d = cg & 63;
      unsigned short* base = vt + ((size_t)(bq*HH + h)*DD + d)*TT;
      #pragma unroll
      for (int m = 0; m < 8; ++m){
        const int t = t0 + wm + m*16 + g*4;
        const int kt = t >> 6;
        const int cch = ((t >> 3) & 7) ^ (d & 7);
        u16x4 pv;
        pv.x = f2bf(acc[m][n][0]); pv.y = f2bf(acc[m][n][1]);
        pv.z = f2bf(acc[m][n][2]); pv.w = f2bf(acc[m][n][3]);
        *(u16x4*)(base + (size_t)kt*64 + cch*8 + (t & 7)) = pv;
      }
    }
    return;
  }

  const float sc = (tsel == 1) ? 0.18033688011112042f : 1.0f;  // log2(e)/8
  unsigned short* outb = (unsigned short*)(tsel == 0 ? o0 : o1);
  #pragma unroll
  for (int m = 0; m < 8; ++m)
    #pragma unroll
    for (int n = 0; n < 4; ++n)
      #pragma unroll
      for (int r = 0; r < 4; ++r){
        const int row = m0 + wm + m*16 + g*4 + r;
        const int col = (n0 & 1023) + wn + n*16 + l15;
        outb[(size_t)row*1024 + col] = f2bf(acc[m][n][r] * sc);
      }
}

// ---------------- proven 128^2 GEMM (used for output projection) ----------------
template<int NX>
__global__ __launch_bounds__(256) void gemm128(const unsigned short* __restrict__ A,
                                               const unsigned short* __restrict__ Bm,
                                               float* __restrict__ o0){
  constexpr int K = 1024;
  constexpr int NWG = NX * 64;
  __shared__ __align__(16) unsigned short As[128*64];
  __shared__ __align__(16) unsigned short Bs[128*64];
  const int tid = threadIdx.x;
  const int flat = blockIdx.y * NX + blockIdx.x;
  const int swz = (flat & 7) * (NWG / 8) + (flat >> 3);
  const int n0 = (swz % NX) * 128;
  const int m0 = (swz / NX) * 128;
  const int w = tid >> 6, lane = tid & 63, l15 = lane & 15, g = lane >> 4;
  const int wm = (w >> 1) * 64, wn = (w & 1) * 64;

  f32x4 acc[4][4] = {};

  for (int k0 = 0; k0 < K; k0 += 64){
    #pragma unroll
    for (int i = 0; i < 4; ++i){
      const int p = i*256 + tid;
      const int r = p >> 3, c = p & 7;
      const int gc = c ^ (r & 7);
      __builtin_amdgcn_global_load_lds(
        (const __attribute__((address_space(1))) void*)(A + (size_t)(m0 + r)*K + k0 + gc*8),
        (__attribute__((address_space(3))) void*)(As + p*8), 16, 0, 0);
    }
    #pragma unroll
    for (int i = 0; i < 4; ++i){
      const int p = i*256 + tid;
      const int r = p >> 3, c = p & 7;
      const int gc = c ^ (r & 7);
      __builtin_amdgcn_global_load_lds(
        (const __attribute__((address_space(1))) void*)(Bm + (size_t)(n0 + r)*K + k0 + gc*8),
        (__attribute__((address_space(3))) void*)(Bs + p*8), 16, 0, 0);
    }
    __syncthreads();

    bf16x8 af[2][4], bfr[2][4];
    #pragma unroll
    for (int ks = 0; ks < 2; ++ks){
      #pragma unroll
      for (int m = 0; m < 4; ++m){
        const int R = wm + m*16 + l15;
        const int c = (ks*4 + g) ^ (R & 7);
        af[ks][m] = as_bf(*(const u16x8*)(As + R*64 + c*8));
      }
      #pragma unroll
      for (int n = 0; n < 4; ++n){
        const int R = wn + n*16 + l15;
        const int c = (ks*4 + g) ^ (R & 7);
        bfr[ks][n] = as_bf(*(const u16x8*)(Bs + R*64 + c*8));
      }
    }
    #pragma unroll
    for (int ks = 0; ks < 2; ++ks)
      #pragma unroll
      for (int m = 0; m < 4; ++m)
        #pragma unroll
        for (int n = 0; n < 4; ++n)
          acc[m][n] = __builtin_amdgcn_mfma_f32_16x16x32_bf16(af[ks][m], bfr[ks][n], acc[m][n], 0, 0, 0);
    __syncthreads();
  }

  #pragma unroll
  for (int m = 0; m < 4; ++m)
    #pragma unroll
    for (int n = 0; n < 4; ++n)
      #pragma unroll
      for (int r = 0; r < 4; ++r){
        const int row = m0 + wm + m*16 + g*4 + r;
        const int col = n0 + wn + n*16 + l15;
        o0[(size_t)row*1024 + col] = acc[m][n][r];
      }
}

// Causal flash attention, swapped-QK 32x32, 8 waves x 32 q-rows = 256 q-rows/block.
// R6-proven: 3-buffer ring, counted vmcnt(2), balanced strip pairing.
__global__ __launch_bounds__(512, 4) void attn2(const unsigned short* __restrict__ Q,
                                                const unsigned short* __restrict__ Km,
                                                const unsigned short* __restrict__ Vt,
                                                unsigned short* __restrict__ Y){
  __shared__ __align__(16) unsigned short Ks[3][64*64];
  __shared__ __align__(16) unsigned short Vs[3][64*64];
  const int bh = blockIdx.x, b = bh >> 4, h = bh & 15;
  const int yq = blockIdx.y;
  const int qt = (yq < 4) ? (7 - yq) : (yq - 4);
  const int tid = threadIdx.x;
  const int w = tid >> 6, lane = tid & 63, l31 = lane & 31, hi = lane >> 5;
  const int q0 = qt * 256;
  const int wq0 = q0 + w * 32;
  const int wqmax = wq0 + 31;
  const int nkt = 4 * qt + 4;
  const int qg = wq0 + l31;

  const unsigned short* Ksrc = Km + (size_t)b*TT*CC + h*DD;
  const unsigned short* Vsrc = Vt + (size_t)bh*DD*TT;

  auto stage = [&](int buf, int kt){
    const int r = tid >> 3, c = tid & 7;
    const int gc = c ^ (r & 7);
    __builtin_amdgcn_global_load_lds(
      (const __attribute__((address_space(1))) void*)(Ksrc + (size_t)(kt*64 + r)*CC + gc*8),
      (__attribute__((address_space(3))) void*)(&Ks[buf][tid*8]), 16, 0, 0);
    __builtin_amdgcn_global_load_lds(
      (const __attribute__((address_space(1))) void*)(Vsrc + (size_t)r*TT + (size_t)kt*64 + c*8),
      (__attribute__((address_space(3))) void*)(&Vs[buf][tid*8]), 16, 0, 0);
  };

  stage(0, 0);

  const unsigned short* qrow = Q + ((size_t)b*TT + wq0 + l31)*CC + h*DD;
  bf16x8 qf[4];
  #pragma unroll
  for (int ds = 0; ds < 4; ++ds)
    qf[ds] = as_bf(*(const u16x8*)(qrow + 16*ds + 8*hi));

  int koff[4];
  #pragma unroll
  for (int ds = 0; ds < 4; ++ds)
    koff[ds] = l31*64 + (((2*ds + hi) ^ (l31 & 7)) * 8);

  float m_ = -1e30f, l_ = 0.f;
  f32x16 y0 = {}, y1 = {};

  int cb = 0;
  for (int t = 0; t < nkt; ++t){
    const int nx = (cb == 2) ? 0 : cb + 1;
    if (t + 1 < nkt){
      stage(nx, t + 1);
      asm volatile("s_waitcnt vmcnt(2)" ::: "memory");
    } else {
      asm volatile("s_waitcnt vmcnt(0)" ::: "memory");
    }
    __builtin_amdgcn_s_barrier();

    if (t*64 <= wqmax){
      const unsigned short* Kp = &Ks[cb][0];
      const unsigned short* Vp = &Vs[cb][0];

      f32x16 s0 = {}, s1 = {};
      __builtin_amdgcn_s_setprio(1);
      #pragma unroll
      for (int ds = 0; ds < 4; ++ds){
        bf16x8 kf0 = as_bf(*(const u16x8*)(Kp + koff[ds]));
        s0 = __builtin_amdgcn_mfma_f32_32x32x16_bf16(kf0, qf[ds], s0, 0, 0, 0);
        bf16x8 kf1 = as_bf(*(const u16x8*)(Kp + koff[ds] + 2048));
        s1 = __builtin_amdgcn_mfma_f32_32x32x16_bf16(kf1, qf[ds], s1, 0, 0, 0);
      }
      __builtin_amdgcn_s_setprio(0);

      if (t*64 + 63 > wq0){
        const int kb0 = t*64;
        #pragma unroll
        for (int r = 0; r < 16; ++r){
          const int kr = (r & 3) + 8*(r >> 2) + 4*hi;
          if (kb0 + kr      > qg) s0[r] = -1e30f;
          if (kb0 + 32 + kr > qg) s1[r] = -1e30f;
        }
      }

      float tm[8];
      #pragma unroll
      for (int r = 0; r < 8; ++r) tm[r] = fmaxf(fmaxf(s0[r], s0[r+8]), fmaxf(s1[r], s1[r+8]));
      #pragma unroll
      for (int r = 0; r < 4; ++r) tm[r] = fmaxf(tm[r], tm[r+4]);
      float pmax = fmaxf(fmaxf(tm[0], tm[2]), fmaxf(tm[1], tm[3]));
      pmax = fmaxf(pmax, __shfl_xor(pmax, 32));

      if (!__all(pmax <= m_ + 8.f)){
        const float mnew = fmaxf(m_, pmax);
        const float alpha = ex2(m_ - mnew);
        l_ *= alpha;
        #pragma unroll
        for (int r = 0; r < 16; ++r){
          const float ar = __shfl(alpha, (r & 3) + 8*(r >> 2) + 4*hi);
          y0[r] *= ar; y1[r] *= ar;
        }
        m_ = mnew;
      }

      #pragma unroll
      for (int r = 0; r < 16; ++r) s0[r] = ex2(s0[r] - m_);
      #pragma unroll
      for (int r = 0; r < 16; ++r) s1[r] = ex2(s1[r] - m_);
      float ts[8];
      #pragma unroll
      for (int r = 0; r < 8; ++r) ts[r] = (s0[r] + s0[r+8]) + (s1[r] + s1[r+8]);
      #pragma unroll
      for (int r = 0; r < 4; ++r) ts[r] += ts[r+4];
      float rs = (ts[0] + ts[2]) + (ts[1] + ts[3]);
      rs += __shfl_xor(rs, 32);
      l_ += rs;

      __builtin_amdgcn_s_setprio(1);
      #pragma unroll
      for (int m = 0; m < 4; ++m){
        const f32x16 c = (m < 2) ? s0 : s1;
        const int bx = (m & 1) * 8;
        unsigned A0 = cvt_pk(c[bx+0], c[bx+1]);
        unsigned B0 = cvt_pk(c[bx+4], c[bx+5]);
        pl32swap(A0, B0);
        unsigned A1 = cvt_pk(c[bx+2], c[bx+3]);
        unsigned B1 = cvt_pk(c[bx+6], c[bx+7]);
        pl32swap(A1, B1);
        u32x4 pw; pw.x = A0; pw.y = A1; pw.z = B0; pw.w = B1;
        const bf16x8 pa = __builtin_bit_cast(bf16x8, pw);
        bf16x8 vf0 = as_bf(*(const u16x8*)(Vp + koff[m]));
        y0 = __builtin_amdgcn_mfma_f32_32x32x16_bf16(pa, vf0, y0, 0, 0, 0);
        bf16x8 vf1 = as_bf(*(const u16x8*)(Vp + koff[m] + 2048));
        y1 = __builtin_amdgcn_mfma_f32_32x32x16_bf16(pa, vf1, y1, 0, 0, 0);
      }
      __builtin_amdgcn_s_setprio(0);
    }
    cb = nx;
  }

  const float linv = 1.f / l_;
  #pragma unroll
  for (int r = 0; r < 16; ++r){
    const int qlr = (r & 3) + 8*(r >> 2) + 4*hi;
    const float lr = __shfl(linv, qlr);
    unsigned short* yp = Y + ((size_t)b*TT + wq0 + qlr)*CC + h*DD + l31;
    yp[0]  = f2bf(y0[r] * lr);
    yp[32] = f2bf(y1[r] * lr);
  }
}

extern "C" void kernel_launch(void* const* d_in, const int* in_sizes, int n_in,
                              void* d_out, int out_size, void* d_ws, size_t ws_size,
                              hipStream_t stream){
  const float* x  = (const float*)d_in[0];
  const float* Wk = (const float*)d_in[1];
  const float* Wq = (const float*)d_in[2];
  const float* Wv = (const float*)d_in[3];
  const float* Wp = (const float*)d_in[4];

  const size_t E  = (size_t)BB*TT*CC;
  const size_t Wn = (size_t)CC*CC;
  unsigned short* ws  = (unsigned short*)d_ws;
  unsigned short* xb  = ws;                 // reused as yb after attention
  unsigned short* wkb = xb  + E;            // wkb,wqb,wvb contiguous = B[3072][1024]
  unsigned short* wqb = wkb + Wn;
  unsigned short* wvb = wqb + Wn;
  unsigned short* wpb = wvb + Wn;
  unsigned short* qb  = wpb + Wn;
  unsigned short* kb  = qb  + E;
  unsigned short* vt  = kb  + E;            // V written transposed by QKV GEMM

  (void)wqb; (void)wvb;

  hipFuncSetAttribute(reinterpret_cast<const void*>(gemm256q<12>),
                      hipFuncAttributeMaxDynamicSharedMemorySize, 131072);

  cvt_all<<<12288, 256, 0, stream>>>(x, Wk, Wq, Wv, Wp, xb, wkb);

  // fused QKV at 256^2: B = [Wk; Wq; Wv] -> kb, qb (scaled), vt (transposed+swizzled)
  gemm256q<12><<<dim3(12, 32), 512, 131072, stream>>>(xb, wkb, kb, qb, vt);

  unsigned short* yb = xb;
  attn2<<<dim3(BB*HH, TT/256), 512, 0, stream>>>(qb, kb, vt, yb);

  gemm128<8><<<dim3(8, 64), 256, 0, stream>>>(yb, wpb, (float*)d_out);
}

// Round 11
// 153.699 us; speedup vs baseline: 1.0373x; 1.0327x over previous
//
#include <hip/hip_runtime.h>

typedef __bf16 bf16x8 __attribute__((ext_vector_type(8)));
typedef float f32x4 __attribute__((ext_vector_type(4)));
typedef float f32x16 __attribute__((ext_vector_type(16)));
typedef unsigned short u16x8 __attribute__((ext_vector_type(8)));
typedef unsigned short u16x4 __attribute__((ext_vector_type(4)));
typedef unsigned u32x4 __attribute__((ext_vector_type(4)));

#define BB 4
#define TT 2048
#define CC 1024
#define HH 16
#define DD 64

__device__ __forceinline__ unsigned short f2bf(float f){
  unsigned u = __builtin_bit_cast(unsigned, f);
  u += 0x7FFFu + ((u >> 16) & 1u);
  return (unsigned short)(u >> 16);
}
__device__ __forceinline__ bf16x8 as_bf(u16x8 v){ return __builtin_bit_cast(bf16x8, v); }
__device__ __forceinline__ unsigned cvt_pk(float lo, float hi){
  unsigned r; asm("v_cvt_pk_bf16_f32 %0, %1, %2" : "=v"(r) : "v"(lo), "v"(hi)); return r;
}
__device__ __forceinline__ void pl32swap(unsigned &a, unsigned &b){
  asm("v_permlane32_swap_b32 %0, %1" : "+v"(a), "+v"(b));
}
__device__ __forceinline__ float ex2(float x){
#if __has_builtin(__builtin_amdgcn_exp2f)
  return __builtin_amdgcn_exp2f(x);
#else
  return __expf(x * 0.6931471805599453f);
#endif
}

// all 5 fp32->bf16 conversions in one launch
__global__ __launch_bounds__(256) void cvt_all(const float* __restrict__ x,
                                               const float* __restrict__ Wk,
                                               const float* __restrict__ Wq,
                                               const float* __restrict__ Wv,
                                               const float* __restrict__ Wp,
                                               unsigned short* __restrict__ xb,
                                               unsigned short* __restrict__ wb){
  const int i = blockIdx.x * 256 + threadIdx.x;           // one float4 per thread
  constexpr int EX = (BB*TT*CC)/4;                        // 2,097,152
  const float* src; unsigned short* dst; int off;
  if (i < EX){ src = x; dst = xb; off = i; }
  else {
    const int j = i - EX;
    const int wsel = j >> 18;                             // Wn/4 = 2^18
    off = j & 262143;
    src = (wsel==0) ? Wk : (wsel==1) ? Wq : (wsel==2) ? Wv : Wp;
    dst = wb + ((size_t)wsel << 20);                      // Wn = 2^20
  }
  const float4 f = ((const float4*)src)[off];
  u16x4 o; o.x = f2bf(f.x); o.y = f2bf(f.y); o.z = f2bf(f.z); o.w = f2bf(f.w);
  ((u16x4*)dst)[off] = o;
}

// ---------------- 256x256 QKV GEMM, fine-interleaved phase pipeline ----------------
// C = A @ B^T, A: 8192x1024 bf16, B: 3072x1024 bf16 ([Wk;Wq;Wv]).
// 512 thr = 8 waves (2M x 4N), per-wave 128x64. LDS: 2 slots x {A,B} x {kh0,kh1} x 256r x 32k
// = 128 KB. Phase = (tile t, ks): stage 4 loads of (t+1,ks) -> vmcnt(8) -> barrier ->
// 12 ds_read -> 32 MFMA. Counted vmcnt: half staged at phase p is consumed at p+2 with
// 2 phases x 4 loads newer in FIFO -> vmcnt(8) proves it landed. No drain in main loop.
// tsel 0 -> K (o0), 1 -> Q (o1, *log2e/8), 2 -> V transposed (o2=Vt).
template<int NX>
__global__ __launch_bounds__(512, 2) void gemm256q(const unsigned short* __restrict__ A,
                                                   const unsigned short* __restrict__ Bm,
                                                   void* __restrict__ o0, void* __restrict__ o1,
                                                   void* __restrict__ o2){
  constexpr int K = 1024;
  constexpr int NKT = 16;
  constexpr int NWG = NX * 32;
  extern __shared__ unsigned short lds[];                 // 2 x 32768 elems (128 KB)
  const int tid = threadIdx.x;
  const int flat = blockIdx.y * NX + blockIdx.x;
  const int swz = (flat & 7) * (NWG / 8) + (flat >> 3);   // bijective (NWG%8==0)
  const int n0 = (swz % NX) * 256;
  const int m0 = (swz / NX) * 256;
  const int w = tid >> 6, lane = tid & 63, l15 = lane & 15, g = lane >> 4;
  const int wm = (w >> 2) * 128;                          // {0,128}
  const int wn = (w & 3) * 64;                            // {0,64,128,192}
  const int tsel = n0 >> 10;                              // block-uniform

  // staging lane constants: row-in-16-block, swizzled global chunk (within 32-k half)
  const int sc_q = lane >> 2;
  const int sc_g = (lane & 3) ^ ((lane >> 3) & 3);
  // reader lane constant: LDS chunk holding this lane's global chunk (g)
  const int rd_cc = g ^ ((l15 >> 1) & 3);

  // stage half ks of tile kt into slot s: 2 A-loads + 2 B-loads (A0,B0,A1,B1)
  auto stage = [&](int s, int kt, int ks){
    #pragma unroll
    for (int j = 0; j < 2; ++j){
      const int wl = j*8 + w;
      const int r = wl*16 + sc_q;
      __builtin_amdgcn_global_load_lds(
        (const __attribute__((address_space(1))) void*)(A + (size_t)(m0 + r)*K + kt*64 + ks*32 + sc_g*8),
        (__attribute__((address_space(3))) void*)(lds + s*32768 + ks*8192 + wl*512 + lane*8), 16, 0, 0);
      __builtin_amdgcn_global_load_lds(
        (const __attribute__((address_space(1))) void*)(Bm + (size_t)(n0 + r)*K + kt*64 + ks*32 + sc_g*8),
        (__attribute__((address_space(3))) void*)(lds + s*32768 + 16384 + ks*8192 + wl*512 + lane*8), 16, 0, 0);
    }
  };

  f32x4 acc[8][4] = {};
  stage(0, 0, 0);
  stage(0, 0, 1);                                        // 8 loads in flight

  for (int t = 0; t < NKT; ++t){
    const int s = t & 1;
    #pragma unroll
    for (int ks = 0; ks < 2; ++ks){
      if (t + 1 < NKT){
        stage(s ^ 1, t + 1, ks);                         // 4 more (12 in flight)
        asm volatile("s_waitcnt vmcnt(8)" ::: "memory"); // half (t,ks) landed; 8 stay in flight
      } else if (ks == 0){
        asm volatile("s_waitcnt vmcnt(4)" ::: "memory"); // tail: (15,0) landed
      } else {
        asm volatile("s_waitcnt vmcnt(0)" ::: "memory");
      }
      __builtin_amdgcn_s_barrier();                      // all waves' halves visible
      asm volatile("" ::: "memory");

      const unsigned short* Asl = lds + s*32768 + ks*8192;
      const unsigned short* Bsl = Asl + 16384;
      bf16x8 bfr[4];
      #pragma unroll
      for (int n = 0; n < 4; ++n)
        bfr[n] = as_bf(*(const u16x8*)(Bsl + (wn + n*16 + l15)*32 + rd_cc*8));
      bf16x8 af[8];
      #pragma unroll
      for (int m = 0; m < 8; ++m)
        af[m] = as_bf(*(const u16x8*)(Asl + (wm + m*16 + l15)*32 + rd_cc*8));

      __builtin_amdgcn_s_setprio(1);
      #pragma unroll
      for (int m = 0; m < 8; ++m)
        #pragma unroll
        for (int n = 0; n < 4; ++n)
          acc[m][n] = __builtin_amdgcn_mfma_f32_16x16x32_bf16(af[m], bfr[n], acc[m][n], 0, 0, 0);
      __builtin_amdgcn_s_setprio(0);
    }
  }

  if (tsel == 2){
    // V epilogue: write transposed to Vt [B*H][D][T] with XOR k-chunk swizzle (u16x4 runs).
    const int bq = m0 >> 11;
    const int t0 = m0 & 2047;
    unsigned short* vt = (unsigned short*)o2;
    #pragma unroll
    for (int n = 0; n < 4; ++n){
      const int cg = (n0 & 1023) + wn + n*16 + l15;        // channel 0..1023
      const int h = cg >> 6, d = cg & 63;
      unsigned short* base = vt + ((size_t)(bq*HH + h)*DD + d)*TT;
      #pragma unroll
      for (int m = 0; m < 8; ++m){
        const int t = t0 + wm + m*16 + g*4;
        const int kt = t >> 6;
        const int cch = ((t >> 3) & 7) ^ (d & 7);
        u16x4 pv;
        pv.x = f2bf(acc[m][n][0]); pv.y = f2bf(acc[m][n][1]);
        pv.z = f2bf(acc[m][n][2]); pv.w = f2bf(acc[m][n][3]);
        *(u16x4*)(base + (size_t)kt*64 + cch*8 + (t & 7)) = pv;
      }
    }
    return;
  }

  const float sc = (tsel == 1) ? 0.18033688011112042f : 1.0f;  // log2(e)/8
  unsigned short* outb = (unsigned short*)(tsel == 0 ? o0 : o1);
  #pragma unroll
  for (int m = 0; m < 8; ++m)
    #pragma unroll
    for (int n = 0; n < 4; ++n)
      #pragma unroll
      for (int r = 0; r < 4; ++r){
        const int row = m0 + wm + m*16 + g*4 + r;
        const int col = (n0 & 1023) + wn + n*16 + l15;
        outb[(size_t)row*1024 + col] = f2bf(acc[m][n][r] * sc);
      }
}

// ---------------- proven 128^2 GEMM (used for output projection) ----------------
template<int NX>
__global__ __launch_bounds__(256) void gemm128(const unsigned short* __restrict__ A,
                                               const unsigned short* __restrict__ Bm,
                                               float* __restrict__ o0){
  constexpr int K = 1024;
  constexpr int NWG = NX * 64;
  __shared__ __align__(16) unsigned short As[128*64];
  __shared__ __align__(16) unsigned short Bs[128*64];
  const int tid = threadIdx.x;
  const int flat = blockIdx.y * NX + blockIdx.x;
  const int swz = (flat & 7) * (NWG / 8) + (flat >> 3);
  const int n0 = (swz % NX) * 128;
  const int m0 = (swz / NX) * 128;
  const int w = tid >> 6, lane = tid & 63, l15 = lane & 15, g = lane >> 4;
  const int wm = (w >> 1) * 64, wn = (w & 1) * 64;

  f32x4 acc[4][4] = {};

  for (int k0 = 0; k0 < K; k0 += 64){
    #pragma unroll
    for (int i = 0; i < 4; ++i){
      const int p = i*256 + tid;
      const int r = p >> 3, c = p & 7;
      const int gc = c ^ (r & 7);
      __builtin_amdgcn_global_load_lds(
        (const __attribute__((address_space(1))) void*)(A + (size_t)(m0 + r)*K + k0 + gc*8),
        (__attribute__((address_space(3))) void*)(As + p*8), 16, 0, 0);
    }
    #pragma unroll
    for (int i = 0; i < 4; ++i){
      const int p = i*256 + tid;
      const int r = p >> 3, c = p & 7;
      const int gc = c ^ (r & 7);
      __builtin_amdgcn_global_load_lds(
        (const __attribute__((address_space(1))) void*)(Bm + (size_t)(n0 + r)*K + k0 + gc*8),
        (__attribute__((address_space(3))) void*)(Bs + p*8), 16, 0, 0);
    }
    __syncthreads();

    bf16x8 af[2][4], bfr[2][4];
    #pragma unroll
    for (int ks = 0; ks < 2; ++ks){
      #pragma unroll
      for (int m = 0; m < 4; ++m){
        const int R = wm + m*16 + l15;
        const int c = (ks*4 + g) ^ (R & 7);
        af[ks][m] = as_bf(*(const u16x8*)(As + R*64 + c*8));
      }
      #pragma unroll
      for (int n = 0; n < 4; ++n){
        const int R = wn + n*16 + l15;
        const int c = (ks*4 + g) ^ (R & 7);
        bfr[ks][n] = as_bf(*(const u16x8*)(Bs + R*64 + c*8));
      }
    }
    #pragma unroll
    for (int ks = 0; ks < 2; ++ks)
      #pragma unroll
      for (int m = 0; m < 4; ++m)
        #pragma unroll
        for (int n = 0; n < 4; ++n)
          acc[m][n] = __builtin_amdgcn_mfma_f32_16x16x32_bf16(af[ks][m], bfr[ks][n], acc[m][n], 0, 0, 0);
    __syncthreads();
  }

  #pragma unroll
  for (int m = 0; m < 4; ++m)
    #pragma unroll
    for (int n = 0; n < 4; ++n)
      #pragma unroll
      for (int r = 0; r < 4; ++r){
        const int row = m0 + wm + m*16 + g*4 + r;
        const int col = n0 + wn + n*16 + l15;
        o0[(size_t)row*1024 + col] = acc[m][n][r];
      }
}

// Causal flash attention, swapped-QK 32x32, 8 waves x 32 q-rows = 256 q-rows/block.
// R6-proven: 3-buffer ring, counted vmcnt(2), balanced strip pairing.
__global__ __launch_bounds__(512, 4) void attn2(const unsigned short* __restrict__ Q,
                                                const unsigned short* __restrict__ Km,
                                                const unsigned short* __restrict__ Vt,
                                                unsigned short* __restrict__ Y){
  __shared__ __align__(16) unsigned short Ks[3][64*64];
  __shared__ __align__(16) unsigned short Vs[3][64*64];
  const int bh = blockIdx.x, b = bh >> 4, h = bh & 15;
  const int yq = blockIdx.y;
  const int qt = (yq < 4) ? (7 - yq) : (yq - 4);
  const int tid = threadIdx.x;
  const int w = tid >> 6, lane = tid & 63, l31 = lane & 31, hi = lane >> 5;
  const int q0 = qt * 256;
  const int wq0 = q0 + w * 32;
  const int wqmax = wq0 + 31;
  const int nkt = 4 * qt + 4;
  const int qg = wq0 + l31;

  const unsigned short* Ksrc = Km + (size_t)b*TT*CC + h*DD;
  const unsigned short* Vsrc = Vt + (size_t)bh*DD*TT;

  auto stage = [&](int buf, int kt){
    const int r = tid >> 3, c = tid & 7;
    const int gc = c ^ (r & 7);
    __builtin_amdgcn_global_load_lds(
      (const __attribute__((address_space(1))) void*)(Ksrc + (size_t)(kt*64 + r)*CC + gc*8),
      (__attribute__((address_space(3))) void*)(&Ks[buf][tid*8]), 16, 0, 0);
    __builtin_amdgcn_global_load_lds(
      (const __attribute__((address_space(1))) void*)(Vsrc + (size_t)r*TT + (size_t)kt*64 + c*8),
      (__attribute__((address_space(3))) void*)(&Vs[buf][tid*8]), 16, 0, 0);
  };

  stage(0, 0);

  const unsigned short* qrow = Q + ((size_t)b*TT + wq0 + l31)*CC + h*DD;
  bf16x8 qf[4];
  #pragma unroll
  for (int ds = 0; ds < 4; ++ds)
    qf[ds] = as_bf(*(const u16x8*)(qrow + 16*ds + 8*hi));

  int koff[4];
  #pragma unroll
  for (int ds = 0; ds < 4; ++ds)
    koff[ds] = l31*64 + (((2*ds + hi) ^ (l31 & 7)) * 8);

  float m_ = -1e30f, l_ = 0.f;
  f32x16 y0 = {}, y1 = {};

  int cb = 0;
  for (int t = 0; t < nkt; ++t){
    const int nx = (cb == 2) ? 0 : cb + 1;
    if (t + 1 < nkt){
      stage(nx, t + 1);
      asm volatile("s_waitcnt vmcnt(2)" ::: "memory");
    } else {
      asm volatile("s_waitcnt vmcnt(0)" ::: "memory");
    }
    __builtin_amdgcn_s_barrier();

    if (t*64 <= wqmax){
      const unsigned short* Kp = &Ks[cb][0];
      const unsigned short* Vp = &Vs[cb][0];

      f32x16 s0 = {}, s1 = {};
      __builtin_amdgcn_s_setprio(1);
      #pragma unroll
      for (int ds = 0; ds < 4; ++ds){
        bf16x8 kf0 = as_bf(*(const u16x8*)(Kp + koff[ds]));
        s0 = __builtin_amdgcn_mfma_f32_32x32x16_bf16(kf0, qf[ds], s0, 0, 0, 0);
        bf16x8 kf1 = as_bf(*(const u16x8*)(Kp + koff[ds] + 2048));
        s1 = __builtin_amdgcn_mfma_f32_32x32x16_bf16(kf1, qf[ds], s1, 0, 0, 0);
      }
      __builtin_amdgcn_s_setprio(0);

      if (t*64 + 63 > wq0){
        const int kb0 = t*64;
        #pragma unroll
        for (int r = 0; r < 16; ++r){
          const int kr = (r & 3) + 8*(r >> 2) + 4*hi;
          if (kb0 + kr      > qg) s0[r] = -1e30f;
          if (kb0 + 32 + kr > qg) s1[r] = -1e30f;
        }
      }

      float tm[8];
      #pragma unroll
      for (int r = 0; r < 8; ++r) tm[r] = fmaxf(fmaxf(s0[r], s0[r+8]), fmaxf(s1[r], s1[r+8]));
      #pragma unroll
      for (int r = 0; r < 4; ++r) tm[r] = fmaxf(tm[r], tm[r+4]);
      float pmax = fmaxf(fmaxf(tm[0], tm[2]), fmaxf(tm[1], tm[3]));
      pmax = fmaxf(pmax, __shfl_xor(pmax, 32));

      if (!__all(pmax <= m_ + 8.f)){
        const float mnew = fmaxf(m_, pmax);
        const float alpha = ex2(m_ - mnew);
        l_ *= alpha;
        #pragma unroll
        for (int r = 0; r < 16; ++r){
          const float ar = __shfl(alpha, (r & 3) + 8*(r >> 2) + 4*hi);
          y0[r] *= ar; y1[r] *= ar;
        }
        m_ = mnew;
      }

      #pragma unroll
      for (int r = 0; r < 16; ++r) s0[r] = ex2(s0[r] - m_);
      #pragma unroll
      for (int r = 0; r < 16; ++r) s1[r] = ex2(s1[r] - m_);
      float ts[8];
      #pragma unroll
      for (int r = 0; r < 8; ++r) ts[r] = (s0[r] + s0[r+8]) + (s1[r] + s1[r+8]);
      #pragma unroll
      for (int r = 0; r < 4; ++r) ts[r] += ts[r+4];
      float rs = (ts[0] + ts[2]) + (ts[1] + ts[3]);
      rs += __shfl_xor(rs, 32);
      l_ += rs;

      __builtin_amdgcn_s_setprio(1);
      #pragma unroll
      for (int m = 0; m < 4; ++m){
        const f32x16 c = (m < 2) ? s0 : s1;
        const int bx = (m & 1) * 8;
        unsigned A0 = cvt_pk(c[bx+0], c[bx+1]);
        unsigned B0 = cvt_pk(c[bx+4], c[bx+5]);
        pl32swap(A0, B0);
        unsigned A1 = cvt_pk(c[bx+2], c[bx+3]);
        unsigned B1 = cvt_pk(c[bx+6], c[bx+7]);
        pl32swap(A1, B1);
        u32x4 pw; pw.x = A0; pw.y = A1; pw.z = B0; pw.w = B1;
        const bf16x8 pa = __builtin_bit_cast(bf16x8, pw);
        bf16x8 vf0 = as_bf(*(const u16x8*)(Vp + koff[m]));
        y0 = __builtin_amdgcn_mfma_f32_32x32x16_bf16(pa, vf0, y0, 0, 0, 0);
        bf16x8 vf1 = as_bf(*(const u16x8*)(Vp + koff[m] + 2048));
        y1 = __builtin_amdgcn_mfma_f32_32x32x16_bf16(pa, vf1, y1, 0, 0, 0);
      }
      __builtin_amdgcn_s_setprio(0);
    }
    cb = nx;
  }

  const float linv = 1.f / l_;
  #pragma unroll
  for (int r = 0; r < 16; ++r){
    const int qlr = (r & 3) + 8*(r >> 2) + 4*hi;
    const float lr = __shfl(linv, qlr);
    unsigned short* yp = Y + ((size_t)b*TT + wq0 + qlr)*CC + h*DD + l31;
    yp[0]  = f2bf(y0[r] * lr);
    yp[32] = f2bf(y1[r] * lr);
  }
}

extern "C" void kernel_launch(void* const* d_in, const int* in_sizes, int n_in,
                              void* d_out, int out_size, void* d_ws, size_t ws_size,
                              hipStream_t stream){
  const float* x  = (const float*)d_in[0];
  const float* Wk = (const float*)d_in[1];
  const float* Wq = (const float*)d_in[2];
  const float* Wv = (const float*)d_in[3];
  const float* Wp = (const float*)d_in[4];

  const size_t E  = (size_t)BB*TT*CC;
  const size_t Wn = (size_t)CC*CC;
  unsigned short* ws  = (unsigned short*)d_ws;
  unsigned short* xb  = ws;                 // reused as yb after attention
  unsigned short* wkb = xb  + E;            // wkb,wqb,wvb contiguous = B[3072][1024]
  unsigned short* wqb = wkb + Wn;
  unsigned short* wvb = wqb + Wn;
  unsigned short* wpb = wvb + Wn;
  unsigned short* qb  = wpb + Wn;
  unsigned short* kb  = qb  + E;
  unsigned short* vt  = kb  + E;            // V written transposed by QKV GEMM

  (void)wqb; (void)wvb;

  hipFuncSetAttribute(reinterpret_cast<const void*>(gemm256q<12>),
                      hipFuncAttributeMaxDynamicSharedMemorySize, 131072);

  cvt_all<<<12288, 256, 0, stream>>>(x, Wk, Wq, Wv, Wp, xb, wkb);

  // fused QKV at 256^2: B = [Wk; Wq; Wv] -> kb, qb (scaled), vt (transposed+swizzled)
  gemm256q<12><<<dim3(12, 32), 512, 131072, stream>>>(xb, wkb, kb, qb, vt);

  unsigned short* yb = xb;
  attn2<<<dim3(BB*HH, TT/256), 512, 0, stream>>>(qb, kb, vt, yb);

  gemm128<8><<<dim3(8, 64), 256, 0, stream>>>(yb, wpb, (float*)d_out);
}

// Round 12
// 152.755 us; speedup vs baseline: 1.0437x; 1.0062x over previous
//
#include <hip/hip_runtime.h>

typedef __bf16 bf16x8 __attribute__((ext_vector_type(8)));
typedef float f32x4 __attribute__((ext_vector_type(4)));
typedef float f32x16 __attribute__((ext_vector_type(16)));
typedef unsigned short u16x8 __attribute__((ext_vector_type(8)));
typedef unsigned short u16x4 __attribute__((ext_vector_type(4)));
typedef unsigned u32x4 __attribute__((ext_vector_type(4)));

#define BB 4
#define TT 2048
#define CC 1024
#define HH 16
#define DD 64

__device__ __forceinline__ unsigned short f2bf(float f){
  unsigned u = __builtin_bit_cast(unsigned, f);
  u += 0x7FFFu + ((u >> 16) & 1u);
  return (unsigned short)(u >> 16);
}
__device__ __forceinline__ bf16x8 as_bf(u16x8 v){ return __builtin_bit_cast(bf16x8, v); }
__device__ __forceinline__ unsigned cvt_pk(float lo, float hi){
  unsigned r; asm("v_cvt_pk_bf16_f32 %0, %1, %2" : "=v"(r) : "v"(lo), "v"(hi)); return r;
}
__device__ __forceinline__ void pl32swap(unsigned &a, unsigned &b){
  asm("v_permlane32_swap_b32 %0, %1" : "+v"(a), "+v"(b));
}
__device__ __forceinline__ float ex2(float x){
#if __has_builtin(__builtin_amdgcn_exp2f)
  return __builtin_amdgcn_exp2f(x);
#else
  return __expf(x * 0.6931471805599453f);
#endif
}

// all 5 fp32->bf16 conversions in one launch
__global__ __launch_bounds__(256) void cvt_all(const float* __restrict__ x,
                                               const float* __restrict__ Wk,
                                               const float* __restrict__ Wq,
                                               const float* __restrict__ Wv,
                                               const float* __restrict__ Wp,
                                               unsigned short* __restrict__ xb,
                                               unsigned short* __restrict__ wb){
  const int i = blockIdx.x * 256 + threadIdx.x;           // one float4 per thread
  constexpr int EX = (BB*TT*CC)/4;                        // 2,097,152
  const float* src; unsigned short* dst; int off;
  if (i < EX){ src = x; dst = xb; off = i; }
  else {
    const int j = i - EX;
    const int wsel = j >> 18;                             // Wn/4 = 2^18
    off = j & 262143;
    src = (wsel==0) ? Wk : (wsel==1) ? Wq : (wsel==2) ? Wv : Wp;
    dst = wb + ((size_t)wsel << 20);                      // Wn = 2^20
  }
  const float4 f = ((const float4*)src)[off];
  u16x4 o; o.x = f2bf(f.x); o.y = f2bf(f.y); o.z = f2bf(f.z); o.w = f2bf(f.w);
  ((u16x4*)dst)[off] = o;
}

// ---------------- 256x256 QKV GEMM, read-ahead phase pipeline ----------------
// C = A @ B^T, A: 8192x1024 bf16, B: 3072x1024 bf16 ([Wk;Wq;Wv]).
// 8 waves (2Mx4N), per-wave 128x64. LDS: 4 half-tile slots x (A 256x32 + B 256x32)
// = 128 KB. Phase p (32-k half): stage(p+3) -> vmcnt(8) -> lgkm(0) -> barrier ->
// MFMA(p) [frags pre-read] -> ds_read(p+1). MFMA never waits on fresh lgkm;
// ds_read(p+1) completes under MFMA(p). Race ledger in round notes.
// tsel 0 -> K (o0), 1 -> Q (o1, *log2e/8), 2 -> V transposed (o2=Vt).
template<int NX>
__global__ __launch_bounds__(512, 2) void gemm256q(const unsigned short* __restrict__ A,
                                                   const unsigned short* __restrict__ Bm,
                                                   void* __restrict__ o0, void* __restrict__ o1,
                                                   void* __restrict__ o2){
  constexpr int K = 1024;
  constexpr int NWG = NX * 32;
  extern __shared__ unsigned short lds[];                 // 4 x 16384 elems (128 KB)
  const int tid = threadIdx.x;
  const int flat = blockIdx.y * NX + blockIdx.x;
  const int swz = (flat & 7) * (NWG / 8) + (flat >> 3);   // bijective (NWG%8==0)
  const int n0 = (swz % NX) * 256;
  const int m0 = (swz / NX) * 256;
  const int w = tid >> 6, lane = tid & 63, l15 = lane & 15, g = lane >> 4;
  const int wm = (w >> 2) * 128;                          // {0,128}
  const int wn = (w & 3) * 64;                            // {0,64,128,192}
  const int tsel = n0 >> 10;                              // block-uniform

  // staging lane constants (same swizzle as proven R10/R11 scheme)
  const int sc_q = lane >> 2;
  const int sc_g = (lane & 3) ^ ((lane >> 3) & 3);
  const int rd_cc = g ^ ((l15 >> 1) & 3);

  // stage half (kt,ks) into slot s: 4 loads/wave (2 A + 2 B)
  auto stage = [&](int s, int kt, int ks){
    #pragma unroll
    for (int j = 0; j < 2; ++j){
      const int wl = j*8 + w;
      const int r = wl*16 + sc_q;
      __builtin_amdgcn_global_load_lds(
        (const __attribute__((address_space(1))) void*)(A + (size_t)(m0 + r)*K + kt*64 + ks*32 + sc_g*8),
        (__attribute__((address_space(3))) void*)(lds + s*16384 + wl*512 + lane*8), 16, 0, 0);
      __builtin_amdgcn_global_load_lds(
        (const __attribute__((address_space(1))) void*)(Bm + (size_t)(n0 + r)*K + kt*64 + ks*32 + sc_g*8),
        (__attribute__((address_space(3))) void*)(lds + s*16384 + 8192 + wl*512 + lane*8), 16, 0, 0);
    }
  };

  int aoff[8], boff[4];
  #pragma unroll
  for (int m = 0; m < 8; ++m) aoff[m] = (wm + m*16 + l15)*32 + rd_cc*8;
  #pragma unroll
  for (int n = 0; n < 4; ++n) boff[n] = 8192 + (wn + n*16 + l15)*32 + rd_cc*8;

  auto dsread = [&](int sbase, bf16x8* af, bf16x8* bfr){
    const unsigned short* base = lds + sbase;
    #pragma unroll
    for (int n = 0; n < 4; ++n) bfr[n] = as_bf(*(const u16x8*)(base + boff[n]));
    #pragma unroll
    for (int m = 0; m < 8; ++m) af[m] = as_bf(*(const u16x8*)(base + aoff[m]));
  };

  f32x4 acc[8][4] = {};
  auto mfma32 = [&](bf16x8* af, bf16x8* bfr){
    __builtin_amdgcn_s_setprio(1);
    #pragma unroll
    for (int m = 0; m < 8; ++m)
      #pragma unroll
      for (int n = 0; n < 4; ++n)
        acc[m][n] = __builtin_amdgcn_mfma_f32_16x16x32_bf16(af[m], bfr[n], acc[m][n], 0, 0, 0);
    __builtin_amdgcn_s_setprio(0);
  };

  bf16x8 afA[8], bfA[4], afB[8], bfB[4];

  // prologue: halves 0,1,2 -> slots 0,1,2; half0 landed -> pre-read set A
  stage(0, 0, 0); stage(1, 0, 1); stage(2, 1, 0);
  asm volatile("s_waitcnt vmcnt(8)" ::: "memory");
  __builtin_amdgcn_s_barrier();
  dsread(0, afA, bfA);

#define PHASE(SSTG, KT, KS, VMC, SRD, AF_U, BF_U, AF_R, BF_R)      \
  do {                                                             \
    if (SSTG >= 0) stage(SSTG, KT, KS);                            \
    asm volatile("s_waitcnt vmcnt(" #VMC ")" ::: "memory");        \
    asm volatile("s_waitcnt lgkmcnt(0)" ::: "memory");             \
    __builtin_amdgcn_s_barrier();                                  \
    __builtin_amdgcn_sched_barrier(0);                             \
    mfma32(AF_U, BF_U);                                            \
    dsread((SRD)*16384, AF_R, BF_R);                               \
  } while (0)

  for (int t = 0; t < 14; t += 2){
    PHASE(3, t+1, 1, 8, 1, afA, bfA, afB, bfB);   // p=2t:   stage half 2t+3, read 2t+1
    PHASE(0, t+2, 0, 8, 2, afB, bfB, afA, bfA);   // p=2t+1: stage half 2t+4, read 2t+2
    PHASE(1, t+2, 1, 8, 3, afA, bfA, afB, bfB);   // p=2t+2: stage half 2t+5, read 2t+3
    PHASE(2, t+3, 0, 8, 0, afB, bfB, afA, bfA);   // p=2t+3: stage half 2t+6, read 2t+4
  }
  // tail: phases 28..31 (tiles 14,15)
  PHASE( 3, 15, 1, 8, 1, afA, bfA, afB, bfB);     // p28: stage half31, read half29
  PHASE(-1,  0, 0, 4, 2, afB, bfB, afA, bfA);     // p29: read half30
  PHASE(-1,  0, 0, 0, 3, afA, bfA, afB, bfB);     // p30: read half31
  asm volatile("s_waitcnt lgkmcnt(0)" ::: "memory");
  __builtin_amdgcn_sched_barrier(0);
  mfma32(afB, bfB);                                // p31
#undef PHASE

  if (tsel == 2){
    // V epilogue: write transposed to Vt [B*H][D][T] with XOR k-chunk swizzle (u16x4 runs).
    const int bq = m0 >> 11;
    const int t0 = m0 & 2047;
    unsigned short* vt = (unsigned short*)o2;
    #pragma unroll
    for (int n = 0; n < 4; ++n){
      const int cg = (n0 & 1023) + wn + n*16 + l15;        // channel 0..1023
      const int h = cg >> 6, d = cg & 63;
      unsigned short* base = vt + ((size_t)(bq*HH + h)*DD + d)*TT;
      #pragma unroll
      for (int m = 0; m < 8; ++m){
        const int t = t0 + wm + m*16 + g*4;
        const int kt = t >> 6;
        const int cch = ((t >> 3) & 7) ^ (d & 7);
        u16x4 pv;
        pv.x = f2bf(acc[m][n][0]); pv.y = f2bf(acc[m][n][1]);
        pv.z = f2bf(acc[m][n][2]); pv.w = f2bf(acc[m][n][3]);
        *(u16x4*)(base + (size_t)kt*64 + cch*8 + (t & 7)) = pv;
      }
    }
    return;
  }

  const float sc = (tsel == 1) ? 0.18033688011112042f : 1.0f;  // log2(e)/8
  unsigned short* outb = (unsigned short*)(tsel == 0 ? o0 : o1);
  #pragma unroll
  for (int m = 0; m < 8; ++m)
    #pragma unroll
    for (int n = 0; n < 4; ++n)
      #pragma unroll
      for (int r = 0; r < 4; ++r){
        const int row = m0 + wm + m*16 + g*4 + r;
        const int col = (n0 & 1023) + wn + n*16 + l15;
        outb[(size_t)row*1024 + col] = f2bf(acc[m][n][r] * sc);
      }
}

// ---------------- proven 128^2 GEMM (used for output projection) ----------------
template<int NX>
__global__ __launch_bounds__(256) void gemm128(const unsigned short* __restrict__ A,
                                               const unsigned short* __restrict__ Bm,
                                               float* __restrict__ o0){
  constexpr int K = 1024;
  constexpr int NWG = NX * 64;
  __shared__ __align__(16) unsigned short As[128*64];
  __shared__ __align__(16) unsigned short Bs[128*64];
  const int tid = threadIdx.x;
  const int flat = blockIdx.y * NX + blockIdx.x;
  const int swz = (flat & 7) * (NWG / 8) + (flat >> 3);
  const int n0 = (swz % NX) * 128;
  const int m0 = (swz / NX) * 128;
  const int w = tid >> 6, lane = tid & 63, l15 = lane & 15, g = lane >> 4;
  const int wm = (w >> 1) * 64, wn = (w & 1) * 64;

  f32x4 acc[4][4] = {};

  for (int k0 = 0; k0 < K; k0 += 64){
    #pragma unroll
    for (int i = 0; i < 4; ++i){
      const int p = i*256 + tid;
      const int r = p >> 3, c = p & 7;
      const int gc = c ^ (r & 7);
      __builtin_amdgcn_global_load_lds(
        (const __attribute__((address_space(1))) void*)(A + (size_t)(m0 + r)*K + k0 + gc*8),
        (__attribute__((address_space(3))) void*)(As + p*8), 16, 0, 0);
    }
    #pragma unroll
    for (int i = 0; i < 4; ++i){
      const int p = i*256 + tid;
      const int r = p >> 3, c = p & 7;
      const int gc = c ^ (r & 7);
      __builtin_amdgcn_global_load_lds(
        (const __attribute__((address_space(1))) void*)(Bm + (size_t)(n0 + r)*K + k0 + gc*8),
        (__attribute__((address_space(3))) void*)(Bs + p*8), 16, 0, 0);
    }
    __syncthreads();

    bf16x8 af[2][4], bfr[2][4];
    #pragma unroll
    for (int ks = 0; ks < 2; ++ks){
      #pragma unroll
      for (int m = 0; m < 4; ++m){
        const int R = wm + m*16 + l15;
        const int c = (ks*4 + g) ^ (R & 7);
        af[ks][m] = as_bf(*(const u16x8*)(As + R*64 + c*8));
      }
      #pragma unroll
      for (int n = 0; n < 4; ++n){
        const int R = wn + n*16 + l15;
        const int c = (ks*4 + g) ^ (R & 7);
        bfr[ks][n] = as_bf(*(const u16x8*)(Bs + R*64 + c*8));
      }
    }
    #pragma unroll
    for (int ks = 0; ks < 2; ++ks)
      #pragma unroll
      for (int m = 0; m < 4; ++m)
        #pragma unroll
        for (int n = 0; n < 4; ++n)
          acc[m][n] = __builtin_amdgcn_mfma_f32_16x16x32_bf16(af[ks][m], bfr[ks][n], acc[m][n], 0, 0, 0);
    __syncthreads();
  }

  #pragma unroll
  for (int m = 0; m < 4; ++m)
    #pragma unroll
    for (int n = 0; n < 4; ++n)
      #pragma unroll
      for (int r = 0; r < 4; ++r){
        const int row = m0 + wm + m*16 + g*4 + r;
        const int col = n0 + wn + n*16 + l15;
        o0[(size_t)row*1024 + col] = acc[m][n][r];
      }
}

// Causal flash attention, swapped-QK 32x32, 8 waves x 32 q-rows = 256 q-rows/block.
// R6-proven: 3-buffer ring, counted vmcnt(2), balanced strip pairing.
__global__ __launch_bounds__(512, 4) void attn2(const unsigned short* __restrict__ Q,
                                                const unsigned short* __restrict__ Km,
                                                const unsigned short* __restrict__ Vt,
                                                unsigned short* __restrict__ Y){
  __shared__ __align__(16) unsigned short Ks[3][64*64];
  __shared__ __align__(16) unsigned short Vs[3][64*64];
  const int bh = blockIdx.x, b = bh >> 4, h = bh & 15;
  const int yq = blockIdx.y;
  const int qt = (yq < 4) ? (7 - yq) : (yq - 4);
  const int tid = threadIdx.x;
  const int w = tid >> 6, lane = tid & 63, l31 = lane & 31, hi = lane >> 5;
  const int q0 = qt * 256;
  const int wq0 = q0 + w * 32;
  const int wqmax = wq0 + 31;
  const int nkt = 4 * qt + 4;
  const int qg = wq0 + l31;

  const unsigned short* Ksrc = Km + (size_t)b*TT*CC + h*DD;
  const unsigned short* Vsrc = Vt + (size_t)bh*DD*TT;

  auto stage = [&](int buf, int kt){
    const int r = tid >> 3, c = tid & 7;
    const int gc = c ^ (r & 7);
    __builtin_amdgcn_global_load_lds(
      (const __attribute__((address_space(1))) void*)(Ksrc + (size_t)(kt*64 + r)*CC + gc*8),
      (__attribute__((address_space(3))) void*)(&Ks[buf][tid*8]), 16, 0, 0);
    __builtin_amdgcn_global_load_lds(
      (const __attribute__((address_space(1))) void*)(Vsrc + (size_t)r*TT + (size_t)kt*64 + c*8),
      (__attribute__((address_space(3))) void*)(&Vs[buf][tid*8]), 16, 0, 0);
  };

  stage(0, 0);

  const unsigned short* qrow = Q + ((size_t)b*TT + wq0 + l31)*CC + h*DD;
  bf16x8 qf[4];
  #pragma unroll
  for (int ds = 0; ds < 4; ++ds)
    qf[ds] = as_bf(*(const u16x8*)(qrow + 16*ds + 8*hi));

  int koff[4];
  #pragma unroll
  for (int ds = 0; ds < 4; ++ds)
    koff[ds] = l31*64 + (((2*ds + hi) ^ (l31 & 7)) * 8);

  float m_ = -1e30f, l_ = 0.f;
  f32x16 y0 = {}, y1 = {};

  int cb = 0;
  for (int t = 0; t < nkt; ++t){
    const int nx = (cb == 2) ? 0 : cb + 1;
    if (t + 1 < nkt){
      stage(nx, t + 1);
      asm volatile("s_waitcnt vmcnt(2)" ::: "memory");
    } else {
      asm volatile("s_waitcnt vmcnt(0)" ::: "memory");
    }
    __builtin_amdgcn_s_barrier();

    if (t*64 <= wqmax){
      const unsigned short* Kp = &Ks[cb][0];
      const unsigned short* Vp = &Vs[cb][0];

      f32x16 s0 = {}, s1 = {};
      __builtin_amdgcn_s_setprio(1);
      #pragma unroll
      for (int ds = 0; ds < 4; ++ds){
        bf16x8 kf0 = as_bf(*(const u16x8*)(Kp + koff[ds]));
        s0 = __builtin_amdgcn_mfma_f32_32x32x16_bf16(kf0, qf[ds], s0, 0, 0, 0);
        bf16x8 kf1 = as_bf(*(const u16x8*)(Kp + koff[ds] + 2048));
        s1 = __builtin_amdgcn_mfma_f32_32x32x16_bf16(kf1, qf[ds], s1, 0, 0, 0);
      }
      __builtin_amdgcn_s_setprio(0);

      if (t*64 + 63 > wq0){
        const int kb0 = t*64;
        #pragma unroll
        for (int r = 0; r < 16; ++r){
          const int kr = (r & 3) + 8*(r >> 2) + 4*hi;
          if (kb0 + kr      > qg) s0[r] = -1e30f;
          if (kb0 + 32 + kr > qg) s1[r] = -1e30f;
        }
      }

      float tm[8];
      #pragma unroll
      for (int r = 0; r < 8; ++r) tm[r] = fmaxf(fmaxf(s0[r], s0[r+8]), fmaxf(s1[r], s1[r+8]));
      #pragma unroll
      for (int r = 0; r < 4; ++r) tm[r] = fmaxf(tm[r], tm[r+4]);
      float pmax = fmaxf(fmaxf(tm[0], tm[2]), fmaxf(tm[1], tm[3]));
      pmax = fmaxf(pmax, __shfl_xor(pmax, 32));

      if (!__all(pmax <= m_ + 8.f)){
        const float mnew = fmaxf(m_, pmax);
        const float alpha = ex2(m_ - mnew);
        l_ *= alpha;
        #pragma unroll
        for (int r = 0; r < 16; ++r){
          const float ar = __shfl(alpha, (r & 3) + 8*(r >> 2) + 4*hi);
          y0[r] *= ar; y1[r] *= ar;
        }
        m_ = mnew;
      }

      #pragma unroll
      for (int r = 0; r < 16; ++r) s0[r] = ex2(s0[r] - m_);
      #pragma unroll
      for (int r = 0; r < 16; ++r) s1[r] = ex2(s1[r] - m_);
      float ts[8];
      #pragma unroll
      for (int r = 0; r < 8; ++r) ts[r] = (s0[r] + s0[r+8]) + (s1[r] + s1[r+8]);
      #pragma unroll
      for (int r = 0; r < 4; ++r) ts[r] += ts[r+4];
      float rs = (ts[0] + ts[2]) + (ts[1] + ts[3]);
      rs += __shfl_xor(rs, 32);
      l_ += rs;

      __builtin_amdgcn_s_setprio(1);
      #pragma unroll
      for (int m = 0; m < 4; ++m){
        const f32x16 c = (m < 2) ? s0 : s1;
        const int bx = (m & 1) * 8;
        unsigned A0 = cvt_pk(c[bx+0], c[bx+1]);
        unsigned B0 = cvt_pk(c[bx+4], c[bx+5]);
        pl32swap(A0, B0);
        unsigned A1 = cvt_pk(c[bx+2], c[bx+3]);
        unsigned B1 = cvt_pk(c[bx+6], c[bx+7]);
        pl32swap(A1, B1);
        u32x4 pw; pw.x = A0; pw.y = A1; pw.z = B0; pw.w = B1;
        const bf16x8 pa = __builtin_bit_cast(bf16x8, pw);
        bf16x8 vf0 = as_bf(*(const u16x8*)(Vp + koff[m]));
        y0 = __builtin_amdgcn_mfma_f32_32x32x16_bf16(pa, vf0, y0, 0, 0, 0);
        bf16x8 vf1 = as_bf(*(const u16x8*)(Vp + koff[m] + 2048));
        y1 = __builtin_amdgcn_mfma_f32_32x32x16_bf16(pa, vf1, y1, 0, 0, 0);
      }
      __builtin_amdgcn_s_setprio(0);
    }
    cb = nx;
  }

  const float linv = 1.f / l_;
  #pragma unroll
  for (int r = 0; r < 16; ++r){
    const int qlr = (r & 3) + 8*(r >> 2) + 4*hi;
    const float lr = __shfl(linv, qlr);
    unsigned short* yp = Y + ((size_t)b*TT + wq0 + qlr)*CC + h*DD + l31;
    yp[0]  = f2bf(y0[r] * lr);
    yp[32] = f2bf(y1[r] * lr);
  }
}

extern "C" void kernel_launch(void* const* d_in, const int* in_sizes, int n_in,
                              void* d_out, int out_size, void* d_ws, size_t ws_size,
                              hipStream_t stream){
  const float* x  = (const float*)d_in[0];
  const float* Wk = (const float*)d_in[1];
  const float* Wq = (const float*)d_in[2];
  const float* Wv = (const float*)d_in[3];
  const float* Wp = (const float*)d_in[4];

  const size_t E  = (size_t)BB*TT*CC;
  const size_t Wn = (size_t)CC*CC;
  unsigned short* ws  = (unsigned short*)d_ws;
  unsigned short* xb  = ws;                 // reused as yb after attention
  unsigned short* wkb = xb  + E;            // wkb,wqb,wvb contiguous = B[3072][1024]
  unsigned short* wqb = wkb + Wn;
  unsigned short* wvb = wqb + Wn;
  unsigned short* wpb = wvb + Wn;
  unsigned short* qb  = wpb + Wn;
  unsigned short* kb  = qb  + E;
  unsigned short* vt  = kb  + E;            // V written transposed by QKV GEMM

  (void)wqb; (void)wvb;

  hipFuncSetAttribute(reinterpret_cast<const void*>(gemm256q<12>),
                      hipFuncAttributeMaxDynamicSharedMemorySize, 131072);

  cvt_all<<<12288, 256, 0, stream>>>(x, Wk, Wq, Wv, Wp, xb, wkb);

  // fused QKV at 256^2: B = [Wk; Wq; Wv] -> kb, qb (scaled), vt (transposed+swizzled)
  gemm256q<12><<<dim3(12, 32), 512, 131072, stream>>>(xb, wkb, kb, qb, vt);

  unsigned short* yb = xb;
  attn2<<<dim3(BB*HH, TT/256), 512, 0, stream>>>(qb, kb, vt, yb);

  gemm128<8><<<dim3(8, 64), 256, 0, stream>>>(yb, wpb, (float*)d_out);
}